// Round 12
// baseline (285.805 us; speedup 1.0000x reference)
//
#include <hip/hip_runtime.h>
#include <math.h>

#define N_NODES 100000
#define N_EDGES 1600000
#define C_DIM 40
#define NGROUPS 6250                      // 100000 / 16 exactly

#define BSZ 256                           // nodes per bucket
#define NB  ((N_NODES + BSZ - 1) / BSZ)   // 391
#define EB  4096                          // edges per hist/scatter block
#define NBE ((N_EDGES + EB - 1) / EB)     // 391

// ---------------- workspace layout (4-byte units) ----------------
#define OFF_DINV 0                        // float[100000]
#define OFF_BB   100000                   // int[NB+1]
#define OFF_CS   100392                   // int[NB] column sums
#define OFF_ROW  100800                   // int[N+1]
#define OFF_H    200802                   // int[NBE*NB]
#define OFF_REC2 353684                   // int2[E] sorted records (even -> 8B aligned)
#define OFF_H1P  3553684                  // ushort[N*64] bf16 h1'; unsorted rec aliases here
#define OFF_H2P  6753684                  // ushort[N*64] bf16 h2' (128B padded rows)
#define OFF_R1P  9953684                  // ushort[N*64] bf16 relu(agg1+b1)

typedef float floatx4 __attribute__((ext_vector_type(4)));
typedef short shortx8 __attribute__((ext_vector_type(8)));

__device__ inline unsigned short f2bf(float f) {
    unsigned int u = __float_as_uint(f);
    u += 0x7FFF + ((u >> 16) & 1);        // round to nearest even
    return (unsigned short)(u >> 16);
}
__device__ inline float bflo(unsigned int u) { return __uint_as_float(u << 16); }
__device__ inline float bfhi(unsigned int u) { return __uint_as_float(u & 0xFFFF0000u); }

// ---------- per-block bucket histogram: H[b][j] + global column sums ----------
__global__ __launch_bounds__(512) void k_hist2d(const int* __restrict__ ei,
                                                int* __restrict__ H,
                                                int* __restrict__ colsum) {
    __shared__ int bins[NB];
    int t = threadIdx.x, b = blockIdx.x;
    for (int i = t; i < NB; i += 512) bins[i] = 0;
    __syncthreads();
    int base = b * EB;
    for (int i = t; i < EB; i += 512) {
        int e = base + i;
        if (e < N_EDGES) atomicAdd(&bins[ei[N_EDGES + e] >> 8], 1);
    }
    __syncthreads();
    for (int i = t; i < NB; i += 512) {
        int c = bins[i];
        H[b * NB + i] = c;
        if (c) atomicAdd(&colsum[i], c);
    }
}

// ---------- column scan (self-computes bucketBase[j] from colsum) ----------
__global__ __launch_bounds__(512) void k_colscan(int* __restrict__ H,
                                                 const int* __restrict__ colsum,
                                                 int* __restrict__ bucketBase,
                                                 int* __restrict__ rowStart) {
    __shared__ int sd[512];
    __shared__ int sbase;
    int t = threadIdx.x, j = blockIdx.x;
    int p = 0;
    for (int i = t; i < j; i += 512) p += colsum[i];
    sd[t] = p;
    __syncthreads();
    for (int off = 256; off > 0; off >>= 1) {
        if (t < off) sd[t] += sd[t + off];
        __syncthreads();
    }
    if (t == 0) sbase = sd[0];
    __syncthreads();
    int base = sbase;
    if (t == 0) {
        bucketBase[j] = base;
        if (j == NB - 1) { bucketBase[NB] = base + colsum[j]; rowStart[N_NODES] = N_EDGES; }
    }
    __syncthreads();
    int val = (t < NBE) ? H[t * NB + j] : 0;
    sd[t] = val;
    __syncthreads();
    for (int off = 1; off < 512; off <<= 1) {
        int v = (t >= off) ? sd[t - off] : 0;
        __syncthreads();
        sd[t] += v;
        __syncthreads();
    }
    if (t < NBE) H[t * NB + j] = base + sd[t] - val;
}

// ---------- scatter: LDS local counting sort, then coalesced run flush ----------
__global__ __launch_bounds__(512) void k_scatter(const int* __restrict__ ei,
                                                 const float* __restrict__ w,
                                                 const int* __restrict__ blockBase,
                                                 int2* __restrict__ rec) {
    __shared__ int2 staged[EB];           // 32 KB
    __shared__ unsigned short sbin[EB];   // 8 KB
    __shared__ int lcnt[NB];
    __shared__ int lbase[NB];
    __shared__ int lcur[NB];
    __shared__ int sd[512];
    int t = threadIdx.x, b = blockIdx.x;
    int base = b * EB;
    int cnt = min(EB, N_EDGES - base);
    for (int i = t; i < NB; i += 512) lcnt[i] = 0;
    __syncthreads();
    int  myBin[8];
    int2 myRec[8];
    int nMine = 0;
    for (int i = t; i < cnt; i += 512) {
        int s = ei[base + i], d = ei[N_EDGES + base + i];
        float wv = w[base + i];
        int bin = d >> 8;
        myBin[nMine] = bin;
        myRec[nMine] = make_int2(s | ((d & 255) << 17), __float_as_int(wv));
        ++nMine;
        atomicAdd(&lcnt[bin], 1);
    }
    __syncthreads();
    int v = (t < NB) ? lcnt[t] : 0;
    sd[t] = v;
    __syncthreads();
    for (int off = 1; off < 512; off <<= 1) {
        int u = (t >= off) ? sd[t - off] : 0;
        __syncthreads();
        sd[t] += u;
        __syncthreads();
    }
    if (t < NB) { lbase[t] = sd[t] - v; lcur[t] = sd[t] - v; }
    __syncthreads();
    for (int k = 0; k < nMine; ++k) {
        int pos = atomicAdd(&lcur[myBin[k]], 1);
        staged[pos] = myRec[k];
        sbin[pos] = (unsigned short)myBin[k];
    }
    __syncthreads();
    for (int i = t; i < cnt; i += 512) {
        int bin = sbin[i];
        rec[blockBase[b * NB + bin] + (i - lbase[bin])] = staged[i];
    }
}

// ---------- per-bucket counting sort; payload = w*dinv[dst]; x = src byte-offset ----------
__global__ __launch_bounds__(512) void k_bsort(const int* __restrict__ bucketBase,
                                               const int2* __restrict__ rec,
                                               int2* __restrict__ rec2,
                                               float* __restrict__ dinv,
                                               int* __restrict__ rowStart) {
    __shared__ int   cnt[256];
    __shared__ float wsum[256];
    __shared__ int   cur[256];
    __shared__ int   sd[512];
    int t = threadIdx.x, b = blockIdx.x;
    if (t < 256) { cnt[t] = 0; wsum[t] = 0.f; }
    __syncthreads();
    int r0 = bucketBase[b], r1 = bucketBase[b + 1];
    for (int i = r0 + t; i < r1; i += 512) {
        int2 rv = rec[i];
        int l = (rv.x >> 17) & 255;
        atomicAdd(&cnt[l], 1);
        atomicAdd(&wsum[l], __int_as_float(rv.y));
    }
    __syncthreads();
    int val = (t < 256) ? cnt[t] : 0;
    sd[t] = val;
    __syncthreads();
    for (int off = 1; off < 512; off <<= 1) {
        int v = (t >= off) ? sd[t - off] : 0;
        __syncthreads();
        sd[t] += v;
        __syncthreads();
    }
    float dloc = 0.f;
    if (t < 256) {
        int excl = sd[t] - val;
        cur[t] = excl;
        int node = b * BSZ + t;
        dloc = rsqrtf(1.f + wsum[t]);
        if (node < N_NODES) {
            rowStart[node] = r0 + excl;
            dinv[node] = dloc;
        }
    }
    __syncthreads();
    if (t < 256) wsum[t] = dloc;
    __syncthreads();
    for (int i = r0 + t; i < r1; i += 512) {
        int2 rv = rec[i];
        int l = (rv.x >> 17) & 255;
        float cpart = __int_as_float(rv.y) * wsum[l];   // w * dinv[dst]
        int pos = r0 + atomicAdd(&cur[l], 1);
        rec2[pos] = make_int2((rv.x & 0x1FFFF) << 7, __float_as_int(cpart));  // src*128B
    }
}

// ---------- h1' = (x @ W1) * dinv[row] via MFMA, stored bf16 ----------
__global__ __launch_bounds__(256) void k_mm1(const float* __restrict__ x,
                                             const float* __restrict__ W1,
                                             const float* __restrict__ dinv,
                                             unsigned short* __restrict__ h1p) {
    int t = threadIdx.x, lane = t & 63, wv = t >> 6;
    int m = lane & 15, quad = lane >> 4;
    int wid = blockIdx.x * 4 + wv, nw = gridDim.x * 4;
    shortx8 B[2][4];
#pragma unroll
    for (int kc = 0; kc < 2; ++kc)
#pragma unroll
        for (int tt = 0; tt < 4; ++tt)
#pragma unroll
            for (int j = 0; j < 8; ++j) {
                int k = kc * 32 + quad * 8 + j;
                B[kc][tt][j] = (short)f2bf(W1[k * 64 + tt * 16 + m]);
            }
    for (int g = wid; g < NGROUPS; g += nw) {
        int n0 = g * 16;
        const float* xr = x + (long)(n0 + m) * 64 + quad * 8;
        floatx4 xa = ((const floatx4*)xr)[0];
        floatx4 xb = ((const floatx4*)(xr + 4))[0];
        floatx4 xc = ((const floatx4*)(xr + 32))[0];
        floatx4 xd = ((const floatx4*)(xr + 36))[0];
        shortx8 A0, A1;
#pragma unroll
        for (int j = 0; j < 4; ++j) {
            A0[j] = (short)f2bf(xa[j]);
            A0[4 + j] = (short)f2bf(xb[j]);
            A1[j] = (short)f2bf(xc[j]);
            A1[4 + j] = (short)f2bf(xd[j]);
        }
        floatx4 acc[4];
#pragma unroll
        for (int tt = 0; tt < 4; ++tt) {
            acc[tt] = (floatx4){0.f, 0.f, 0.f, 0.f};
            acc[tt] = __builtin_amdgcn_mfma_f32_16x16x32_bf16(A0, B[0][tt], acc[tt], 0, 0, 0);
            acc[tt] = __builtin_amdgcn_mfma_f32_16x16x32_bf16(A1, B[1][tt], acc[tt], 0, 0, 0);
        }
        floatx4 dv = ((const floatx4*)(dinv + n0 + quad * 4))[0];
#pragma unroll
        for (int reg = 0; reg < 4; ++reg) {
            int node = n0 + quad * 4 + reg;
            float d = dv[reg];
#pragma unroll
            for (int tt = 0; tt < 4; ++tt)
                h1p[(long)node * 64 + tt * 16 + m] = f2bf(acc[tt][reg] * d);
        }
    }
}

// ---------- agg1: 4 edge-slots x 16 lanes, 4 row-loads in flight ----------
// Epilogue fuses relu(acc+b1) -> bf16 r1p.
__global__ __launch_bounds__(256) void k_agg1(const int* __restrict__ rowStart,
                                              const int2* __restrict__ rec2,
                                              const float* __restrict__ dinv,
                                              const unsigned short* __restrict__ h1p,
                                              const float* __restrict__ b1,
                                              unsigned short* __restrict__ r1p) {
    __shared__ int2 cache[4][64];
    int t = threadIdx.x, lane = t & 63, wv = t >> 6;
    int node = blockIdx.x * 4 + wv;
    if (node >= N_NODES) return;
    int2* wc = cache[wv];
    wc[lane] = make_int2(0, 0);
    const char* hb = (const char*)h1p;
    int eslot = lane >> 4;                // 0..3
    int c = lane & 15;                    // cols 4c..4c+3
    int lo = c << 3;
    float dn = dinv[node];
    float a0 = 0, a1 = 0, a2 = 0, a3 = 0;
    float g0 = 0, g1 = 0, g2 = 0, g3 = 0;
    if (eslot == 0) {                     // self loop: h1'*dinv = h1*dinv^2
        uint2 u = *(const uint2*)(hb + ((long)node << 7) + lo);
        a0 = bflo(u.x) * dn; a1 = bfhi(u.x) * dn;
        a2 = bflo(u.y) * dn; a3 = bfhi(u.y) * dn;
    }
    int s0 = rowStart[node], s1 = rowStart[node + 1];
    for (int base = s0; base < s1; base += 64) {
        int idx = base + lane;
        if (idx < s1) wc[lane] = rec2[idx];
        __builtin_amdgcn_wave_barrier();
        int cnt = min(64, s1 - base);
        int j = 0;
        for (; j + 15 < cnt; j += 16) {
            int2 e0 = wc[j + eslot];
            int2 e1 = wc[j + 4 + eslot];
            int2 e2 = wc[j + 8 + eslot];
            int2 e3 = wc[j + 12 + eslot];
            uint2 u0 = *(const uint2*)(hb + e0.x + lo);
            uint2 u1 = *(const uint2*)(hb + e1.x + lo);
            uint2 u2 = *(const uint2*)(hb + e2.x + lo);
            uint2 u3 = *(const uint2*)(hb + e3.x + lo);
            float c0 = __int_as_float(e0.y), c1 = __int_as_float(e1.y);
            float c2 = __int_as_float(e2.y), c3 = __int_as_float(e3.y);
            a0 = fmaf(bflo(u0.x), c0, a0); a1 = fmaf(bfhi(u0.x), c0, a1);
            a2 = fmaf(bflo(u0.y), c0, a2); a3 = fmaf(bfhi(u0.y), c0, a3);
            g0 = fmaf(bflo(u1.x), c1, g0); g1 = fmaf(bfhi(u1.x), c1, g1);
            g2 = fmaf(bflo(u1.y), c1, g2); g3 = fmaf(bfhi(u1.y), c1, g3);
            a0 = fmaf(bflo(u2.x), c2, a0); a1 = fmaf(bfhi(u2.x), c2, a1);
            a2 = fmaf(bflo(u2.y), c2, a2); a3 = fmaf(bfhi(u2.y), c2, a3);
            g0 = fmaf(bflo(u3.x), c3, g0); g1 = fmaf(bfhi(u3.x), c3, g1);
            g2 = fmaf(bflo(u3.y), c3, g2); g3 = fmaf(bfhi(u3.y), c3, g3);
        }
        for (; j < cnt; j += 4) {
            int jj = j + eslot;
            bool valid = jj < cnt;
            int2 e = wc[valid ? jj : j];
            float cc = valid ? __int_as_float(e.y) : 0.f;
            uint2 u = *(const uint2*)(hb + e.x + lo);
            a0 = fmaf(bflo(u.x), cc, a0); a1 = fmaf(bfhi(u.x), cc, a1);
            a2 = fmaf(bflo(u.y), cc, a2); a3 = fmaf(bfhi(u.y), cc, a3);
        }
        __builtin_amdgcn_wave_barrier();
    }
    a0 += g0; a1 += g1; a2 += g2; a3 += g3;
#define RED(v) v += __shfl_xor(v, 16, 64); v += __shfl_xor(v, 32, 64)
    RED(a0); RED(a1); RED(a2); RED(a3);
#undef RED
    if (eslot == 0) {
        floatx4 bv = ((const floatx4*)(b1 + (c << 2)))[0];
        unsigned int w0 = f2bf(fmaxf(a0 + bv[0], 0.f)) |
                          ((unsigned int)f2bf(fmaxf(a1 + bv[1], 0.f)) << 16);
        unsigned int w1 = f2bf(fmaxf(a2 + bv[2], 0.f)) |
                          ((unsigned int)f2bf(fmaxf(a3 + bv[3], 0.f)) << 16);
        *(uint2*)(r1p + ((long)node << 6) + (c << 2)) = make_uint2(w0, w1);
    }
}

// ---------- h2' = (r1' @ W2) * dinv via MFMA (bf16 in), 128B-padded rows ----------
__global__ __launch_bounds__(256) void k_mm2(const unsigned short* __restrict__ r1p,
                                             const float* __restrict__ W2,
                                             const float* __restrict__ dinv,
                                             unsigned short* __restrict__ h2p) {
    int t = threadIdx.x, lane = t & 63, wv = t >> 6;
    int m = lane & 15, quad = lane >> 4;
    int wid = blockIdx.x * 4 + wv, nw = gridDim.x * 4;
    shortx8 B[2][3];
#pragma unroll
    for (int kc = 0; kc < 2; ++kc)
#pragma unroll
        for (int tt = 0; tt < 3; ++tt) {
            int n = tt * 16 + m;
#pragma unroll
            for (int j = 0; j < 8; ++j) {
                int k = kc * 32 + quad * 8 + j;
                B[kc][tt][j] = (n < C_DIM) ? (short)f2bf(W2[k * C_DIM + n]) : (short)0;
            }
        }
    for (int g = wid; g < NGROUPS; g += nw) {
        int n0 = g * 16;
        const unsigned short* rr = r1p + ((long)(n0 + m) << 6) + quad * 8;
        shortx8 A0 = *(const shortx8*)rr;
        shortx8 A1 = *(const shortx8*)(rr + 32);
        floatx4 acc[3];
#pragma unroll
        for (int tt = 0; tt < 3; ++tt) {
            acc[tt] = (floatx4){0.f, 0.f, 0.f, 0.f};
            acc[tt] = __builtin_amdgcn_mfma_f32_16x16x32_bf16(A0, B[0][tt], acc[tt], 0, 0, 0);
            acc[tt] = __builtin_amdgcn_mfma_f32_16x16x32_bf16(A1, B[1][tt], acc[tt], 0, 0, 0);
        }
        floatx4 dv = ((const floatx4*)(dinv + n0 + quad * 4))[0];
#pragma unroll
        for (int reg = 0; reg < 4; ++reg) {
            int node = n0 + quad * 4 + reg;
            float d = dv[reg];
#pragma unroll
            for (int tt = 0; tt < 3; ++tt) {
                int col = tt * 16 + m;
                if (col < C_DIM)
                    h2p[((long)node << 6) + col] = f2bf(acc[tt][reg] * d);
            }
        }
    }
}

// ---------- agg2: 4 edge-slots x 16 lanes (10 active cols), 4 loads in flight ----------
__global__ __launch_bounds__(256) void k_agg2(const int* __restrict__ rowStart,
                                              const int2* __restrict__ rec2,
                                              const float* __restrict__ dinv,
                                              const unsigned short* __restrict__ h2p,
                                              const float* __restrict__ b2,
                                              float* __restrict__ out) {
    __shared__ int2 cache[4][64];
    int t = threadIdx.x, lane = t & 63, wv = t >> 6;
    int node = blockIdx.x * 4 + wv;
    if (node >= N_NODES) return;
    int2* wc = cache[wv];
    wc[lane] = make_int2(0, 0);
    const char* hb = (const char*)h2p;
    int eslot = lane >> 4;                // 0..3
    int c = lane & 15;                    // cols 4c..4c+3 (c>=10: clamped dup of c=9)
    bool act = c < 10;
    int lo = (act ? c : 9) << 3;
    float dn = dinv[node];
    float a0 = 0, a1 = 0, a2 = 0, a3 = 0;
    float g0 = 0, g1 = 0, g2 = 0, g3 = 0;
    if (eslot == 0) {                     // self loop
        uint2 u = *(const uint2*)(hb + ((long)node << 7) + lo);
        a0 = bflo(u.x) * dn; a1 = bfhi(u.x) * dn;
        a2 = bflo(u.y) * dn; a3 = bfhi(u.y) * dn;
    }
    int s0 = rowStart[node], s1 = rowStart[node + 1];
    for (int base = s0; base < s1; base += 64) {
        int idx = base + lane;
        if (idx < s1) wc[lane] = rec2[idx];
        __builtin_amdgcn_wave_barrier();
        int cnt = min(64, s1 - base);
        int j = 0;
        for (; j + 15 < cnt; j += 16) {
            int2 e0 = wc[j + eslot];
            int2 e1 = wc[j + 4 + eslot];
            int2 e2 = wc[j + 8 + eslot];
            int2 e3 = wc[j + 12 + eslot];
            uint2 u0 = *(const uint2*)(hb + e0.x + lo);
            uint2 u1 = *(const uint2*)(hb + e1.x + lo);
            uint2 u2 = *(const uint2*)(hb + e2.x + lo);
            uint2 u3 = *(const uint2*)(hb + e3.x + lo);
            float c0 = __int_as_float(e0.y), c1 = __int_as_float(e1.y);
            float c2 = __int_as_float(e2.y), c3 = __int_as_float(e3.y);
            a0 = fmaf(bflo(u0.x), c0, a0); a1 = fmaf(bfhi(u0.x), c0, a1);
            a2 = fmaf(bflo(u0.y), c0, a2); a3 = fmaf(bfhi(u0.y), c0, a3);
            g0 = fmaf(bflo(u1.x), c1, g0); g1 = fmaf(bfhi(u1.x), c1, g1);
            g2 = fmaf(bflo(u1.y), c1, g2); g3 = fmaf(bfhi(u1.y), c1, g3);
            a0 = fmaf(bflo(u2.x), c2, a0); a1 = fmaf(bfhi(u2.x), c2, a1);
            a2 = fmaf(bflo(u2.y), c2, a2); a3 = fmaf(bfhi(u2.y), c2, a3);
            g0 = fmaf(bflo(u3.x), c3, g0); g1 = fmaf(bfhi(u3.x), c3, g1);
            g2 = fmaf(bflo(u3.y), c3, g2); g3 = fmaf(bfhi(u3.y), c3, g3);
        }
        for (; j < cnt; j += 4) {
            int jj = j + eslot;
            bool valid = jj < cnt;
            int2 e = wc[valid ? jj : j];
            float cc = valid ? __int_as_float(e.y) : 0.f;
            uint2 u = *(const uint2*)(hb + e.x + lo);
            a0 = fmaf(bflo(u.x), cc, a0); a1 = fmaf(bfhi(u.x), cc, a1);
            a2 = fmaf(bflo(u.y), cc, a2); a3 = fmaf(bfhi(u.y), cc, a3);
        }
        __builtin_amdgcn_wave_barrier();
    }
    a0 += g0; a1 += g1; a2 += g2; a3 += g3;
#define RED(v) v += __shfl_xor(v, 16, 64); v += __shfl_xor(v, 32, 64)
    RED(a0); RED(a1); RED(a2); RED(a3);
#undef RED
    floatx4 bb = act ? ((const floatx4*)(b2 + (c << 2)))[0] : (floatx4){0, 0, 0, 0};
    float v0 = act ? a0 + bb[0] : -INFINITY;
    float v1 = act ? a1 + bb[1] : -INFINITY;
    float v2 = act ? a2 + bb[2] : -INFINITY;
    float v3 = act ? a3 + bb[3] : -INFINITY;
    float m = fmaxf(fmaxf(v0, v1), fmaxf(v2, v3));
    m = fmaxf(m, __shfl_xor(m, 1, 64));
    m = fmaxf(m, __shfl_xor(m, 2, 64));
    m = fmaxf(m, __shfl_xor(m, 4, 64));
    m = fmaxf(m, __shfl_xor(m, 8, 64));
    float s = act ? (expf(v0 - m) + expf(v1 - m)) + (expf(v2 - m) + expf(v3 - m)) : 0.f;
    s += __shfl_xor(s, 1, 64);
    s += __shfl_xor(s, 2, 64);
    s += __shfl_xor(s, 4, 64);
    s += __shfl_xor(s, 8, 64);
    float ls = m + logf(s);
    if (eslot == 0 && act) {
        *(float4*)(out + (long)node * C_DIM + (c << 2)) =
            make_float4(v0 - ls, v1 - ls, v2 - ls, v3 - ls);
    }
}

extern "C" void kernel_launch(void* const* d_in, const int* in_sizes, int n_in,
                              void* d_out, int out_size, void* d_ws, size_t ws_size,
                              hipStream_t stream) {
    const float* x  = (const float*)d_in[0];
    const int*   ei = (const int*)d_in[1];
    const float* w  = (const float*)d_in[2];
    const float* W1 = (const float*)d_in[3];
    const float* b1 = (const float*)d_in[4];
    const float* W2 = (const float*)d_in[5];
    const float* b2 = (const float*)d_in[6];
    float* out = (float*)d_out;

    float* wsf = (float*)d_ws;
    int*   wsi = (int*)d_ws;
    float* dinv       = wsf + OFF_DINV;
    int*   bucketBase = wsi + OFF_BB;
    int*   colsum     = wsi + OFF_CS;
    int*   rowStart   = wsi + OFF_ROW;
    int*   H          = wsi + OFF_H;
    int2*  rec2       = (int2*)(wsi + OFF_REC2);
    int2*  rec        = (int2*)(wsi + OFF_H1P);              // dead before h1p written
    unsigned short* h1p = (unsigned short*)(wsi + OFF_H1P);
    unsigned short* h2p = (unsigned short*)(wsi + OFF_H2P);
    unsigned short* r1p = (unsigned short*)(wsi + OFF_R1P);

    // CSR build — zero global atomics except 391-bin colsum
    hipMemsetAsync(colsum, 0, NB * sizeof(int), stream);
    k_hist2d<<<NBE, 512, 0, stream>>>(ei, H, colsum);
    k_colscan<<<NB, 512, 0, stream>>>(H, colsum, bucketBase, rowStart);
    k_scatter<<<NBE, 512, 0, stream>>>(ei, w, H, rec);
    k_bsort<<<NB, 512, 0, stream>>>(bucketBase, rec, rec2, dinv, rowStart);

    // layer 1 (MFMA matmul + gather-aggregate w/ fused relu+bias epilogue)
    k_mm1<<<1024, 256, 0, stream>>>(x, W1, dinv, h1p);
    k_agg1<<<(N_NODES + 3) / 4, 256, 0, stream>>>(rowStart, rec2, dinv, h1p, b1, r1p);

    // layer 2 (MFMA matmul + gather-aggregate w/ fused bias/log-softmax)
    k_mm2<<<1024, 256, 0, stream>>>(r1p, W2, dinv, h2p);
    k_agg2<<<(N_NODES + 3) / 4, 256, 0, stream>>>(rowStart, rec2, dinv, h2p, b2, out);
}